// Round 3
// baseline (209.795 us; speedup 1.0000x reference)
//
#include <hip/hip_runtime.h>

#define NM    4096
#define NPTS  131072
#define CAP   128
#define NV    4            // voxels per persistent block
#define NBLK  (NM / NV)    // 1024 blocks

typedef _Float16 h8 __attribute__((ext_vector_type(8)));
typedef _Float16 h2 __attribute__((ext_vector_type(2)));
typedef float    f4 __attribute__((ext_vector_type(4)));
typedef int      i4 __attribute__((ext_vector_type(4)));

#define MF(a, b, c) __builtin_amdgcn_mfma_f32_16x16x32_f16((a), (b), (c), 0, 0, 0)

static __device__ inline h2 pk(float a, float b) {
    return __builtin_bit_cast(h2, __builtin_amdgcn_cvt_pkrtz(a, b));
}

static __device__ inline h8 pack8(float u0, float u1, float u2, float u3,
                                  float u4, float u5, float u6, float u7) {
    i4 t;
    t[0] = __builtin_bit_cast(int, pk(u0, u1));
    t[1] = __builtin_bit_cast(int, pk(u2, u3));
    t[2] = __builtin_bit_cast(int, pk(u4, u5));
    t[3] = __builtin_bit_cast(int, pk(u6, u7));
    return __builtin_bit_cast(h8, t);
}

// 8 guarded f16 from an fp32 row in LDS (reads unconditional + select).
static __device__ inline h8 lds_row8(const float* __restrict__ X, int base,
                                     int d0, int lim) {
    float u[8];
    #pragma unroll
    for (int jj = 0; jj < 8; jj++) {
        int d = d0 + jj;
        float raw = X[base + d];          // always in-bounds of the buffer
        u[jj] = (d < lim) ? raw : 0.f;
    }
    return pack8(u[0], u[1], u[2], u[3], u[4], u[5], u[6], u[7]);
}

// aligned 8-float (32B) run in LDS -> h8 (two ds_read_b128)
static __device__ inline h8 lds_row8a(const float* __restrict__ X, int off) {
    f4 v0 = *(const f4*)(X + off);
    f4 v1 = *(const f4*)(X + off + 4);
    return pack8(v0[0], v0[1], v0[2], v0[3], v1[0], v1[1], v1[2], v1[3]);
}

// NeRF frequency-encoding dim d of (x,y,z); 0 for d >= lim.
static __device__ inline float encdim(int d, int lim, float x, float y, float z) {
    int tt = d - 3;
    int k  = tt / 6;
    int r  = tt - 6 * k;
    float p = x;
    p = (r == 1 || r == 4) ? y : p;
    p = (r == 2 || r == 5) ? z : p;
    float f   = __int_as_float((k + 127) << 23);   // 2^k
    float arg = p * f + ((r >= 3) ? 1.57079632679f : 0.f);  // cos = sin(+pi/2)
    float sv  = __sinf(arg);
    float raw = (d == 0) ? x : ((d == 1) ? y : z);
    float val = (d < 3) ? raw : sv;
    return (d < lim) ? val : 0.f;
}

// D-frag pair -> B-frag (verified in R8; see R8 notes for derivation).
static __device__ inline h8 makeB(f4 d0, f4 d1, int quad, int col) {
    int laneA = ((quad & 1) * 2) * 16 + col;
    int laneB = laneA + 16;
    float a0 = __shfl(d0[0], laneA), b0 = __shfl(d1[0], laneA);
    float a1 = __shfl(d0[1], laneA), b1 = __shfl(d1[1], laneA);
    float a2 = __shfl(d0[2], laneA), b2 = __shfl(d1[2], laneA);
    float a3 = __shfl(d0[3], laneA), b3 = __shfl(d1[3], laneA);
    float a4 = __shfl(d0[0], laneB), b4 = __shfl(d1[0], laneB);
    float a5 = __shfl(d0[1], laneB), b5 = __shfl(d1[1], laneB);
    float a6 = __shfl(d0[2], laneB), b6 = __shfl(d1[2], laneB);
    float a7 = __shfl(d0[3], laneB), b7 = __shfl(d1[3], laneB);
    bool hi = quad >= 2;
    return pack8(hi ? b0 : a0, hi ? b1 : a1, hi ? b2 : a2, hi ? b3 : a3,
                 hi ? b4 : a4, hi ? b5 : a5, hi ? b6 : a6, hi ? b7 : a7);
}

static __device__ inline f4 relu4(f4 a) {
    f4 r;
    r[0] = fmaxf(a[0], 0.f); r[1] = fmaxf(a[1], 0.f);
    r[2] = fmaxf(a[2], 0.f); r[3] = fmaxf(a[3], 0.f);
    return r;
}

__global__ __launch_bounds__(256) void k_bucket(const float* __restrict__ pts,
                                                int* __restrict__ count,
                                                int* __restrict__ plist) {
    int n = blockIdx.x * 256 + threadIdx.x;
    if (n >= NPTS) return;
    float x = pts[3 * n + 0], y = pts[3 * n + 1], z = pts[3 * n + 2];
    int ix = (int)fminf(fmaxf(x * 16.f, 0.f), 15.f);
    int iy = (int)fminf(fmaxf(y * 16.f, 0.f), 15.f);
    int iz = (int)fminf(fmaxf(z * 16.f, 0.f), 15.f);
    int v = (ix << 8) | (iy << 4) | iz;
    int pos = atomicAdd(&count[v], 1);
    if (pos < CAP) plist[v * CAP + pos] = n;
}

// R11 = R10 pipeline + WAR fix: snapshot the point-prefetch registers
// (nn/npx..ndz) BEFORE issuing next voxel's nextptA (R10 clobbered nn before
// the snapshot -> outputs written to the wrong point indices, absmax 0.40).
//
// Persistent 4-voxel blocks + double-buffered register-staged weights:
//   stage_write(X[cur]) ; barrier ; snapshot pts ; issue loads(v+1)->regs ;
//   unpack ; nextptB(v+1) ; compute
// Weight loads are consumed by ds_write BEFORE the barrier (T14), so the
// barrier's vmcnt drain never kills the next voxel's prefetch, which stays
// in flight across the whole unpack+compute phase. Buffer b rewritten at
// iv+2 is ordered after the iv+1 barrier, which post-dates all iv unpacks.
// LDS layout per buffer: w0@0(2016) w1@2016(1024) vw@3040(1888) fw@4928(1024)
// sw@5952(32) rw@5984(96) -> 6080 f, 2 buffers.
__global__ __launch_bounds__(256) void k_mlp(
    const float* __restrict__ pts, const float* __restrict__ vds,
    const float* __restrict__ w0g, const float* __restrict__ b0g,
    const float* __restrict__ w1g, const float* __restrict__ b1g,
    const float* __restrict__ fwg, const float* __restrict__ fbg,
    const float* __restrict__ swg, const float* __restrict__ sbg,
    const float* __restrict__ vwg, const float* __restrict__ vbg,
    const float* __restrict__ rwg, const float* __restrict__ rbg,
    const int* __restrict__ count, const int* __restrict__ plist,
    float* __restrict__ out) {
    __shared__ __align__(16) float X[2][6080];   // 48640 B

    const int bid  = blockIdx.x;
    const int t    = threadIdx.x;
    const int wid  = t >> 6;
    const int lane = t & 63;
    const int col  = lane & 15;
    const int quad = lane >> 4;
    const int k8   = quad * 8;
    const int vbase = bid * NV;

    int cs[NV];
    #pragma unroll
    for (int iv = 0; iv < NV; iv++) cs[iv] = min(count[vbase + iv], CAP);

    f4 sreg[8];

    // ---- per-wave staging roles ----
    auto stage_issue = [&](int v) {
        if (wid == 0) {
            const float* g = w0g + (size_t)v * 2016;
            #pragma unroll
            for (int k = 0; k < 7; k++) sreg[k] = *(const f4*)(g + k * 256 + lane * 4);
            sreg[7] = (lane < 56) ? *(const f4*)(g + 1792 + lane * 4) : f4{0.f, 0.f, 0.f, 0.f};
        } else if (wid == 1) {
            const float* g = vwg + (size_t)v * 1888;
            #pragma unroll
            for (int k = 0; k < 7; k++) sreg[k] = *(const f4*)(g + k * 256 + lane * 4);
            sreg[7] = (lane < 24) ? *(const f4*)(g + 1792 + lane * 4) : f4{0.f, 0.f, 0.f, 0.f};
        } else if (wid == 2) {
            const float* g = w1g + (size_t)v * 1024;
            #pragma unroll
            for (int k = 0; k < 4; k++) sreg[k] = *(const f4*)(g + k * 256 + lane * 4);
            sreg[4] = (lane < 8)  ? *(const f4*)(swg + (size_t)v * 32 + lane * 4) : f4{0.f, 0.f, 0.f, 0.f};
            sreg[5] = (lane < 24) ? *(const f4*)(rwg + (size_t)v * 96 + lane * 4) : f4{0.f, 0.f, 0.f, 0.f};
        } else {
            const float* g = fwg + (size_t)v * 1024;
            #pragma unroll
            for (int k = 0; k < 4; k++) sreg[k] = *(const f4*)(g + k * 256 + lane * 4);
        }
    };

    auto stage_write = [&](float* Xb) {
        if (wid == 0) {
            #pragma unroll
            for (int k = 0; k < 7; k++) *(f4*)(Xb + k * 256 + lane * 4) = sreg[k];
            if (lane < 56) *(f4*)(Xb + 1792 + lane * 4) = sreg[7];
        } else if (wid == 1) {
            #pragma unroll
            for (int k = 0; k < 7; k++) *(f4*)(Xb + 3040 + k * 256 + lane * 4) = sreg[k];
            if (lane < 24) *(f4*)(Xb + 4832 + lane * 4) = sreg[7];
        } else if (wid == 2) {
            #pragma unroll
            for (int k = 0; k < 4; k++) *(f4*)(Xb + 2016 + k * 256 + lane * 4) = sreg[k];
            if (lane < 8)  *(f4*)(Xb + 5952 + lane * 4) = sreg[4];
            if (lane < 24) *(f4*)(Xb + 5984 + lane * 4) = sreg[5];
        } else {
            #pragma unroll
            for (int k = 0; k < 4; k++) *(f4*)(Xb + 4928 + k * 256 + lane * 4) = sreg[k];
        }
    };

    // ---- point-data prefetch, one voxel ahead, two issue phases ----
    int   nn = 0;
    float npx = 0.f, npy = 0.f, npz = 0.f, ndx = 0.f, ndy = 0.f, ndz = 0.f;
    auto nextptA = [&](int iv) {                 // phase A: plist gather
        int c = cs[iv];
        if (wid * 16 < c) {
            int sl = min(wid * 16 + col, c - 1);
            nn = plist[(vbase + iv) * CAP + sl];
        }
    };
    auto nextptB = [&](int iv) {                 // phase B: pts/vds gather
        int c = cs[iv];
        if (wid * 16 < c) {
            npx = pts[3 * nn]; npy = pts[3 * nn + 1]; npz = pts[3 * nn + 2];
            int ray = nn >> 7;
            ndx = vds[3 * ray]; ndy = vds[3 * ray + 1]; ndz = vds[3 * ray + 2];
        }
    };

    // ---- prologue: voxel 0 in flight ----
    stage_issue(vbase);
    nextptA(0);
    nextptB(0);

    const f4 z4 = {0.f, 0.f, 0.f, 0.f};

    for (int iv = 0; iv < NV; iv++) {
        float* Xb = X[iv & 1];
        stage_write(Xb);                 // drains this voxel's weight loads
        __syncthreads();                 // LDS visible; prev buffer free

        // SNAPSHOT current voxel's prefetched point data BEFORE nextptA(iv+1)
        // overwrites nn (this was R10's bug).
        int ncur = nn;
        float pxc = npx, pyc = npy, pzc = npz;
        float dxc = ndx, dyc = ndy, dzc = ndz;

        if (iv + 1 < NV) {               // next voxel's stream: in flight
            stage_issue(vbase + iv + 1); //   during unpack + compute below
            nextptA(iv + 1);
        }

        const int c = cs[iv];
        const bool hasWork = (wid * 16) < c;

        if (hasWork) {
            // biases: small arrays, L2/L3-warm; hidden under unpack
            f4 cB0[2], cB1[2], cFB[2], cVB[2];
            #pragma unroll
            for (int Ti = 0; Ti < 2; Ti++) {
                #pragma unroll
                for (int r = 0; r < 4; r++) {
                    int row = Ti * 16 + quad * 4 + r;
                    int vv = vbase + iv;
                    cB0[Ti][r] = b0g[vv * 32 + row];
                    cB1[Ti][r] = b1g[vv * 32 + row];
                    cFB[Ti][r] = fbg[vv * 32 + row];
                    cVB[Ti][r] = vbg[vv * 32 + row];
                }
            }
            const float rb0 = rbg[(vbase + iv) * 3 + 0];
            const float rb1 = rbg[(vbase + iv) * 3 + 1];
            const float rb2 = rbg[(vbase + iv) * 3 + 2];
            const float sb  = sbg[vbase + iv];

            // ---- unpack fragments from LDS ----
            h8 aW0[2][2], aVW[2][2], aW1[2], aFW[2], aSG, aRGB;
            #pragma unroll
            for (int Ti = 0; Ti < 2; Ti++) {
                int r0 = (Ti * 16 + col) * 63;
                aW0[Ti][0] = lds_row8(Xb, r0, k8, 63);
                aW0[Ti][1] = lds_row8(Xb, r0, 32 + k8, 63);
                aW1[Ti] = lds_row8a(Xb, 2016 + (Ti * 16 + col) * 32 + k8);
                int r1 = 3040 + (Ti * 16 + col) * 59;
                aVW[Ti][0] = lds_row8(Xb, r1, k8, 59);
                aVW[Ti][1] = lds_row8(Xb, r1, 32 + k8, 59);
                aFW[Ti] = lds_row8a(Xb, 4928 + (Ti * 16 + col) * 32 + k8);
            }
            aSG  = (col == 0) ? lds_row8a(Xb, 5952 + k8) : h8{};
            aRGB = (col < 3) ? lds_row8a(Xb, 5984 + col * 32 + k8) : h8{};

            // phase B of next voxel's point gather: plist value has landed by
            // now (issued before unpack); dependent gathers overlap compute.
            if (iv + 1 < NV) nextptB(iv + 1);

            for (int base = wid * 16; base < c; base += 64) {
                const bool active = (base + col) < c;
                const int n = ncur;
                const float px = pxc, py = pyc, pz = pzc;
                const float dx = dxc, dy = dyc, dz = dzc;

                if (base + 64 < c) {
                    int sl = min(base + 64 + col, c - 1);
                    ncur = plist[(vbase + iv) * CAP + sl];
                    pxc = pts[3 * ncur]; pyc = pts[3 * ncur + 1]; pzc = pts[3 * ncur + 2];
                    int ray = ncur >> 7;
                    dxc = vds[3 * ray]; dyc = vds[3 * ray + 1]; dzc = vds[3 * ray + 2];
                }

                h8 bE0 = pack8(encdim(k8 + 0, 63, px, py, pz), encdim(k8 + 1, 63, px, py, pz),
                               encdim(k8 + 2, 63, px, py, pz), encdim(k8 + 3, 63, px, py, pz),
                               encdim(k8 + 4, 63, px, py, pz), encdim(k8 + 5, 63, px, py, pz),
                               encdim(k8 + 6, 63, px, py, pz), encdim(k8 + 7, 63, px, py, pz));
                h8 bE1 = pack8(encdim(32 + k8 + 0, 63, px, py, pz), encdim(32 + k8 + 1, 63, px, py, pz),
                               encdim(32 + k8 + 2, 63, px, py, pz), encdim(32 + k8 + 3, 63, px, py, pz),
                               encdim(32 + k8 + 4, 63, px, py, pz), encdim(32 + k8 + 5, 63, px, py, pz),
                               encdim(32 + k8 + 6, 63, px, py, pz), encdim(32 + k8 + 7, 63, px, py, pz));

                // layer 0
                f4 d0 = MF(aW0[0][0], bE0, cB0[0]); d0 = MF(aW0[0][1], bE1, d0);
                f4 d1 = MF(aW0[1][0], bE0, cB0[1]); d1 = MF(aW0[1][1], bE1, d1);
                d0 = relu4(d0); d1 = relu4(d1);
                h8 bH = makeB(d0, d1, quad, col);

                // layer 1
                f4 e0 = MF(aW1[0], bH, cB1[0]);
                f4 e1 = MF(aW1[1], bH, cB1[1]);
                e0 = relu4(e0); e1 = relu4(e1);
                h8 bG = makeB(e0, e1, quad, col);

                // sigma
                f4 s = MF(aSG, bG, z4);

                // feature
                f4 f0 = MF(aFW[0], bG, cFB[0]);
                f4 f1 = MF(aFW[1], bG, cFB[1]);
                h8 bF = makeB(f0, f1, quad, col);

                // dir encoding
                h8 bD = pack8(encdim(k8 + 0, 27, dx, dy, dz), encdim(k8 + 1, 27, dx, dy, dz),
                              encdim(k8 + 2, 27, dx, dy, dz), encdim(k8 + 3, 27, dx, dy, dz),
                              encdim(k8 + 4, 27, dx, dy, dz), encdim(k8 + 5, 27, dx, dy, dz),
                              encdim(k8 + 6, 27, dx, dy, dz), encdim(k8 + 7, 27, dx, dy, dz));

                // view layer
                f4 v0 = MF(aVW[0][0], bF, cVB[0]); v0 = MF(aVW[0][1], bD, v0);
                f4 v1 = MF(aVW[1][0], bF, cVB[1]); v1 = MF(aVW[1][1], bD, v1);
                v0 = relu4(v0); v1 = relu4(v1);
                h8 bV = makeB(v0, v1, quad, col);

                // rgb
                f4 o = MF(aRGB, bV, z4);

                if (quad == 0 && active) {
                    out[3 * n + 0] = o[0] + rb0;
                    out[3 * n + 1] = o[1] + rb1;
                    out[3 * n + 2] = o[2] + rb2;
                    out[3 * NPTS + n] = s[0] + sb;
                }
            }
        } else {
            if (iv + 1 < NV) nextptB(iv + 1);
        }
    }
}

extern "C" void kernel_launch(void* const* d_in, const int* in_sizes, int n_in,
                              void* d_out, int out_size, void* d_ws, size_t ws_size,
                              hipStream_t stream) {
    const float* pts = (const float*)d_in[0];
    const float* vds = (const float*)d_in[1];
    const float* w0  = (const float*)d_in[2];
    const float* b0  = (const float*)d_in[3];
    const float* w1  = (const float*)d_in[4];
    const float* b1  = (const float*)d_in[5];
    const float* fw  = (const float*)d_in[6];
    const float* fb  = (const float*)d_in[7];
    const float* sw  = (const float*)d_in[8];
    const float* sb  = (const float*)d_in[9];
    const float* vw  = (const float*)d_in[10];
    const float* vb  = (const float*)d_in[11];
    const float* rw  = (const float*)d_in[12];
    const float* rb  = (const float*)d_in[13];
    float* out = (float*)d_out;

    int* count = (int*)d_ws;
    int* plist = (int*)((char*)d_ws + NM * sizeof(int));

    (void)hipMemsetAsync(count, 0, NM * sizeof(int), stream);
    k_bucket<<<NPTS / 256, 256, 0, stream>>>(pts, count, plist);
    k_mlp<<<NBLK, 256, 0, stream>>>(pts, vds, w0, b0, w1, b1, fw, fb, sw, sb,
                                    vw, vb, rw, rb, count, plist, out);
}

// Round 4
// 177.078 us; speedup vs baseline: 1.1848x; 1.1848x over previous
//
#include <hip/hip_runtime.h>

#define NM    4096
#define NPTS  131072
#define CAP   128
#define NV    4            // voxels per persistent block
#define NBLK  (NM / NV)    // 1024 blocks

typedef _Float16 h8 __attribute__((ext_vector_type(8)));
typedef _Float16 h2 __attribute__((ext_vector_type(2)));
typedef float    f4 __attribute__((ext_vector_type(4)));
typedef int      i4 __attribute__((ext_vector_type(4)));

#define MF(a, b, c) __builtin_amdgcn_mfma_f32_16x16x32_f16((a), (b), (c), 0, 0, 0)

#if __has_builtin(__builtin_amdgcn_global_load_lds)
#define USE_DMA 1
#else
#define USE_DMA 0
#endif

static __device__ inline h2 pk(float a, float b) {
    return __builtin_bit_cast(h2, __builtin_amdgcn_cvt_pkrtz(a, b));
}

static __device__ inline h8 pack8(float u0, float u1, float u2, float u3,
                                  float u4, float u5, float u6, float u7) {
    i4 t;
    t[0] = __builtin_bit_cast(int, pk(u0, u1));
    t[1] = __builtin_bit_cast(int, pk(u2, u3));
    t[2] = __builtin_bit_cast(int, pk(u4, u5));
    t[3] = __builtin_bit_cast(int, pk(u6, u7));
    return __builtin_bit_cast(h8, t);
}

// 8 guarded f16 from an fp32 row in LDS (reads unconditional + select).
static __device__ inline h8 lds_row8(const float* __restrict__ X, int base,
                                     int d0, int lim) {
    float u[8];
    #pragma unroll
    for (int jj = 0; jj < 8; jj++) {
        int d = d0 + jj;
        float raw = X[base + d];          // always in-bounds of the buffer
        u[jj] = (d < lim) ? raw : 0.f;
    }
    return pack8(u[0], u[1], u[2], u[3], u[4], u[5], u[6], u[7]);
}

// aligned 8-float (32B) run in LDS -> h8 (two ds_read_b128)
static __device__ inline h8 lds_row8a(const float* __restrict__ X, int off) {
    f4 v0 = *(const f4*)(X + off);
    f4 v1 = *(const f4*)(X + off + 4);
    return pack8(v0[0], v0[1], v0[2], v0[3], v1[0], v1[1], v1[2], v1[3]);
}

// 8 guarded f16 from a global fp32 row (fallback path, no DMA builtin).
static __device__ inline h8 load_row8(const float* __restrict__ rb, int d0, int lim) {
    float u[8];
    #pragma unroll
    for (int jj = 0; jj < 8; jj++) {
        int d = d0 + jj;
        u[jj] = (d < lim) ? rb[d] : 0.f;
    }
    return pack8(u[0], u[1], u[2], u[3], u[4], u[5], u[6], u[7]);
}

// NeRF frequency-encoding dim d of (x,y,z); 0 for d >= lim.
static __device__ inline float encdim(int d, int lim, float x, float y, float z) {
    int tt = d - 3;
    int k  = tt / 6;
    int r  = tt - 6 * k;
    float p = x;
    p = (r == 1 || r == 4) ? y : p;
    p = (r == 2 || r == 5) ? z : p;
    float f   = __int_as_float((k + 127) << 23);   // 2^k
    float arg = p * f + ((r >= 3) ? 1.57079632679f : 0.f);  // cos = sin(+pi/2)
    float sv  = __sinf(arg);
    float raw = (d == 0) ? x : ((d == 1) ? y : z);
    float val = (d < 3) ? raw : sv;
    return (d < lim) ? val : 0.f;
}

// D-frag pair -> B-frag (verified in R8; see R8 notes for derivation).
static __device__ inline h8 makeB(f4 d0, f4 d1, int quad, int col) {
    int laneA = ((quad & 1) * 2) * 16 + col;
    int laneB = laneA + 16;
    float a0 = __shfl(d0[0], laneA), b0 = __shfl(d1[0], laneA);
    float a1 = __shfl(d0[1], laneA), b1 = __shfl(d1[1], laneA);
    float a2 = __shfl(d0[2], laneA), b2 = __shfl(d1[2], laneA);
    float a3 = __shfl(d0[3], laneA), b3 = __shfl(d1[3], laneA);
    float a4 = __shfl(d0[0], laneB), b4 = __shfl(d1[0], laneB);
    float a5 = __shfl(d0[1], laneB), b5 = __shfl(d1[1], laneB);
    float a6 = __shfl(d0[2], laneB), b6 = __shfl(d1[2], laneB);
    float a7 = __shfl(d0[3], laneB), b7 = __shfl(d1[3], laneB);
    bool hi = quad >= 2;
    return pack8(hi ? b0 : a0, hi ? b1 : a1, hi ? b2 : a2, hi ? b3 : a3,
                 hi ? b4 : a4, hi ? b5 : a5, hi ? b6 : a6, hi ? b7 : a7);
}

static __device__ inline f4 relu4(f4 a) {
    f4 r;
    r[0] = fmaxf(a[0], 0.f); r[1] = fmaxf(a[1], 0.f);
    r[2] = fmaxf(a[2], 0.f); r[3] = fmaxf(a[3], 0.f);
    return r;
}

#if USE_DMA
static __device__ inline void dma16(const float* g, const float* l) {
    __builtin_amdgcn_global_load_lds(
        (const __attribute__((address_space(1))) void*)g,
        (__attribute__((address_space(3))) void*)l, 16, 0, 0);
}
#endif

__global__ __launch_bounds__(256) void k_bucket(const float* __restrict__ pts,
                                                int* __restrict__ count,
                                                int* __restrict__ plist) {
    int n = blockIdx.x * 256 + threadIdx.x;
    if (n >= NPTS) return;
    float x = pts[3 * n + 0], y = pts[3 * n + 1], z = pts[3 * n + 2];
    int ix = (int)fminf(fmaxf(x * 16.f, 0.f), 15.f);
    int iy = (int)fminf(fmaxf(y * 16.f, 0.f), 15.f);
    int iz = (int)fminf(fmaxf(z * 16.f, 0.f), 15.f);
    int v = (ix << 8) | (iy << 4) | iz;
    int pos = atomicAdd(&count[v], 1);
    if (pos < CAP) plist[v * CAP + pos] = n;
}

// R12: persistent 4-voxel pipeline (R11 structure, verified correct) with
// global_load_lds DMA staging instead of register staging.
// R11 post-mortem: sreg[8] (32 VGPRs) live across the barrier + 56 VGPRs of
// fragments spilled to scratch -> 99 MB of spill traffic (WRITE_SIZE 10->109
// MB) ~= 48 us of the 79 us dispatch. DMA staging needs ZERO staging VGPRs.
// With persistent blocks the barrier drain is harmless: dma(iv+1) is issued
// right after barrier(iv) and drained at barrier(iv+1) -- a full voxel's
// unpack+compute (~2-3 us) in between (m97 double-buffer pattern).
//   prologue: dma(v0 -> X[0])
//   iter iv:  barrier (drains dma iv) ; snapshot pts ; dma(iv+1 -> X[iv+1&1])
//             ; unpack X[iv&1] ; nextptB(iv+1) ; compute
// Point-prefetch snapshot BEFORE nextptA(iv+1) (R10's WAR bug, fixed in R11).
// LDS layout per buffer: w0@0(2016) w1@2016(1024) vw@3040(1888) fw@4928(1024)
// sw@5952(32) rw@5984(96) -> 6080 f, 2 buffers = 48640 B.
__global__ __launch_bounds__(256, 1) void k_mlp(
    const float* __restrict__ pts, const float* __restrict__ vds,
    const float* __restrict__ w0g, const float* __restrict__ b0g,
    const float* __restrict__ w1g, const float* __restrict__ b1g,
    const float* __restrict__ fwg, const float* __restrict__ fbg,
    const float* __restrict__ swg, const float* __restrict__ sbg,
    const float* __restrict__ vwg, const float* __restrict__ vbg,
    const float* __restrict__ rwg, const float* __restrict__ rbg,
    const int* __restrict__ count, const int* __restrict__ plist,
    float* __restrict__ out) {
    __shared__ __align__(16) float X[2][6080];   // 48640 B

    const int bid  = blockIdx.x;
    const int t    = threadIdx.x;
    const int wid  = t >> 6;
    const int lane = t & 63;
    const int col  = lane & 15;
    const int quad = lane >> 4;
    const int k8   = quad * 8;
    const int vbase = bid * NV;

    int cs[NV];
    #pragma unroll
    for (int iv = 0; iv < NV; iv++) cs[iv] = min(count[vbase + iv], CAP);

#if USE_DMA
    // ---- per-wave DMA staging roles (layout verified in R9) ----
    auto dma_stage = [&](int v, float* Xb) {
        if (wid == 0) {
            const float* g = w0g + (size_t)v * 2016;
            #pragma unroll
            for (int k = 0; k < 7; k++) dma16(g + k * 256 + lane * 4, Xb + k * 256);
            if (lane < 56) dma16(g + 1792 + lane * 4, Xb + 1792);
        } else if (wid == 1) {
            const float* g = vwg + (size_t)v * 1888;
            #pragma unroll
            for (int k = 0; k < 7; k++) dma16(g + k * 256 + lane * 4, Xb + 3040 + k * 256);
            if (lane < 24) dma16(g + 1792 + lane * 4, Xb + 4832);
        } else if (wid == 2) {
            const float* g = w1g + (size_t)v * 1024;
            #pragma unroll
            for (int k = 0; k < 4; k++) dma16(g + k * 256 + lane * 4, Xb + 2016 + k * 256);
            if (lane < 8)  dma16(swg + (size_t)v * 32 + lane * 4, Xb + 5952);
            if (lane < 24) dma16(rwg + (size_t)v * 96 + lane * 4, Xb + 5984);
        } else {
            const float* g = fwg + (size_t)v * 1024;
            #pragma unroll
            for (int k = 0; k < 4; k++) dma16(g + k * 256 + lane * 4, Xb + 4928 + k * 256);
        }
    };
#endif

    // ---- point-data prefetch, one voxel ahead, two issue phases ----
    int   nn = 0;
    float npx = 0.f, npy = 0.f, npz = 0.f, ndx = 0.f, ndy = 0.f, ndz = 0.f;
    auto nextptA = [&](int iv) {                 // phase A: plist gather
        int c = cs[iv];
        if (wid * 16 < c) {
            int sl = min(wid * 16 + col, c - 1);
            nn = plist[(vbase + iv) * CAP + sl];
        }
    };
    auto nextptB = [&](int iv) {                 // phase B: pts/vds gather
        int c = cs[iv];
        if (wid * 16 < c) {
            npx = pts[3 * nn]; npy = pts[3 * nn + 1]; npz = pts[3 * nn + 2];
            int ray = nn >> 7;
            ndx = vds[3 * ray]; ndy = vds[3 * ray + 1]; ndz = vds[3 * ray + 2];
        }
    };

    // ---- prologue: voxel 0's weights + point data in flight ----
#if USE_DMA
    dma_stage(vbase, X[0]);
#endif
    nextptA(0);
    nextptB(0);

    const f4 z4 = {0.f, 0.f, 0.f, 0.f};

    for (int iv = 0; iv < NV; iv++) {
        float* Xb = X[iv & 1];
#if USE_DMA
        __syncthreads();   // drains dma(iv): buffer iv&1 complete & visible
#endif

        // SNAPSHOT current voxel's prefetched point data BEFORE nextptA(iv+1)
        // overwrites nn (R10's WAR bug; order verified correct in R11).
        int ncur = nn;
        float pxc = npx, pyc = npy, pzc = npz;
        float dxc = ndx, dyc = ndy, dzc = ndz;

        if (iv + 1 < NV) {
#if USE_DMA
            dma_stage(vbase + iv + 1, X[(iv + 1) & 1]);  // lands during compute
#endif
            nextptA(iv + 1);
        }

        const int c = cs[iv];
        const bool hasWork = (wid * 16) < c;

        if (hasWork) {
            // biases: small arrays, L2/L3-warm; hidden under unpack
            f4 cB0[2], cB1[2], cFB[2], cVB[2];
            #pragma unroll
            for (int Ti = 0; Ti < 2; Ti++) {
                #pragma unroll
                for (int r = 0; r < 4; r++) {
                    int row = Ti * 16 + quad * 4 + r;
                    int vv = vbase + iv;
                    cB0[Ti][r] = b0g[vv * 32 + row];
                    cB1[Ti][r] = b1g[vv * 32 + row];
                    cFB[Ti][r] = fbg[vv * 32 + row];
                    cVB[Ti][r] = vbg[vv * 32 + row];
                }
            }
            const float rb0 = rbg[(vbase + iv) * 3 + 0];
            const float rb1 = rbg[(vbase + iv) * 3 + 1];
            const float rb2 = rbg[(vbase + iv) * 3 + 2];
            const float sb  = sbg[vbase + iv];

            // ---- unpack fragments ----
            h8 aW0[2][2], aVW[2][2], aW1[2], aFW[2], aSG, aRGB;
#if USE_DMA
            #pragma unroll
            for (int Ti = 0; Ti < 2; Ti++) {
                int r0 = (Ti * 16 + col) * 63;
                aW0[Ti][0] = lds_row8(Xb, r0, k8, 63);
                aW0[Ti][1] = lds_row8(Xb, r0, 32 + k8, 63);
                aW1[Ti] = lds_row8a(Xb, 2016 + (Ti * 16 + col) * 32 + k8);
                int r1 = 3040 + (Ti * 16 + col) * 59;
                aVW[Ti][0] = lds_row8(Xb, r1, k8, 59);
                aVW[Ti][1] = lds_row8(Xb, r1, 32 + k8, 59);
                aFW[Ti] = lds_row8a(Xb, 4928 + (Ti * 16 + col) * 32 + k8);
            }
            aSG  = (col == 0) ? lds_row8a(Xb, 5952 + k8) : h8{};
            aRGB = (col < 3) ? lds_row8a(Xb, 5984 + col * 32 + k8) : h8{};
#else
            {
                int vv = vbase + iv;
                #pragma unroll
                for (int Ti = 0; Ti < 2; Ti++) {
                    const float* rb = w0g + (size_t)vv * 2016 + (Ti * 16 + col) * 63;
                    aW0[Ti][0] = load_row8(rb, k8, 63);
                    aW0[Ti][1] = load_row8(rb, 32 + k8, 63);
                    rb = vwg + (size_t)vv * 1888 + (Ti * 16 + col) * 59;
                    aVW[Ti][0] = load_row8(rb, k8, 59);
                    aVW[Ti][1] = load_row8(rb, 32 + k8, 59);
                    aW1[Ti] = load_row8(w1g + (size_t)vv * 1024 + (Ti * 16 + col) * 32, k8, 32);
                    aFW[Ti] = load_row8(fwg + (size_t)vv * 1024 + (Ti * 16 + col) * 32, k8, 32);
                }
                aSG  = (col == 0) ? load_row8(swg + (size_t)vv * 32, k8, 32) : h8{};
                aRGB = (col < 3) ? load_row8(rwg + (size_t)vv * 96 + col * 32, k8, 32) : h8{};
            }
#endif

            // phase B of next voxel's point gather: plist value has landed by
            // now (issued before unpack); dependent gathers overlap compute.
            if (iv + 1 < NV) nextptB(iv + 1);

            for (int base = wid * 16; base < c; base += 64) {
                const bool active = (base + col) < c;
                const int n = ncur;
                const float px = pxc, py = pyc, pz = pzc;
                const float dx = dxc, dy = dyc, dz = dzc;

                if (base + 64 < c) {
                    int sl = min(base + 64 + col, c - 1);
                    ncur = plist[(vbase + iv) * CAP + sl];
                    pxc = pts[3 * ncur]; pyc = pts[3 * ncur + 1]; pzc = pts[3 * ncur + 2];
                    int ray = ncur >> 7;
                    dxc = vds[3 * ray]; dyc = vds[3 * ray + 1]; dzc = vds[3 * ray + 2];
                }

                h8 bE0 = pack8(encdim(k8 + 0, 63, px, py, pz), encdim(k8 + 1, 63, px, py, pz),
                               encdim(k8 + 2, 63, px, py, pz), encdim(k8 + 3, 63, px, py, pz),
                               encdim(k8 + 4, 63, px, py, pz), encdim(k8 + 5, 63, px, py, pz),
                               encdim(k8 + 6, 63, px, py, pz), encdim(k8 + 7, 63, px, py, pz));
                h8 bE1 = pack8(encdim(32 + k8 + 0, 63, px, py, pz), encdim(32 + k8 + 1, 63, px, py, pz),
                               encdim(32 + k8 + 2, 63, px, py, pz), encdim(32 + k8 + 3, 63, px, py, pz),
                               encdim(32 + k8 + 4, 63, px, py, pz), encdim(32 + k8 + 5, 63, px, py, pz),
                               encdim(32 + k8 + 6, 63, px, py, pz), encdim(32 + k8 + 7, 63, px, py, pz));

                // layer 0
                f4 d0 = MF(aW0[0][0], bE0, cB0[0]); d0 = MF(aW0[0][1], bE1, d0);
                f4 d1 = MF(aW0[1][0], bE0, cB0[1]); d1 = MF(aW0[1][1], bE1, d1);
                d0 = relu4(d0); d1 = relu4(d1);
                h8 bH = makeB(d0, d1, quad, col);

                // layer 1
                f4 e0 = MF(aW1[0], bH, cB1[0]);
                f4 e1 = MF(aW1[1], bH, cB1[1]);
                e0 = relu4(e0); e1 = relu4(e1);
                h8 bG = makeB(e0, e1, quad, col);

                // sigma
                f4 s = MF(aSG, bG, z4);

                // feature
                f4 f0 = MF(aFW[0], bG, cFB[0]);
                f4 f1 = MF(aFW[1], bG, cFB[1]);
                h8 bF = makeB(f0, f1, quad, col);

                // dir encoding
                h8 bD = pack8(encdim(k8 + 0, 27, dx, dy, dz), encdim(k8 + 1, 27, dx, dy, dz),
                              encdim(k8 + 2, 27, dx, dy, dz), encdim(k8 + 3, 27, dx, dy, dz),
                              encdim(k8 + 4, 27, dx, dy, dz), encdim(k8 + 5, 27, dx, dy, dz),
                              encdim(k8 + 6, 27, dx, dy, dz), encdim(k8 + 7, 27, dx, dy, dz));

                // view layer
                f4 v0 = MF(aVW[0][0], bF, cVB[0]); v0 = MF(aVW[0][1], bD, v0);
                f4 v1 = MF(aVW[1][0], bF, cVB[1]); v1 = MF(aVW[1][1], bD, v1);
                v0 = relu4(v0); v1 = relu4(v1);
                h8 bV = makeB(v0, v1, quad, col);

                // rgb
                f4 o = MF(aRGB, bV, z4);

                if (quad == 0 && active) {
                    out[3 * n + 0] = o[0] + rb0;
                    out[3 * n + 1] = o[1] + rb1;
                    out[3 * n + 2] = o[2] + rb2;
                    out[3 * NPTS + n] = s[0] + sb;
                }
            }
        } else {
            if (iv + 1 < NV) nextptB(iv + 1);
        }
    }
}

extern "C" void kernel_launch(void* const* d_in, const int* in_sizes, int n_in,
                              void* d_out, int out_size, void* d_ws, size_t ws_size,
                              hipStream_t stream) {
    const float* pts = (const float*)d_in[0];
    const float* vds = (const float*)d_in[1];
    const float* w0  = (const float*)d_in[2];
    const float* b0  = (const float*)d_in[3];
    const float* w1  = (const float*)d_in[4];
    const float* b1  = (const float*)d_in[5];
    const float* fw  = (const float*)d_in[6];
    const float* fb  = (const float*)d_in[7];
    const float* sw  = (const float*)d_in[8];
    const float* sb  = (const float*)d_in[9];
    const float* vw  = (const float*)d_in[10];
    const float* vb  = (const float*)d_in[11];
    const float* rw  = (const float*)d_in[12];
    const float* rb  = (const float*)d_in[13];
    float* out = (float*)d_out;

    int* count = (int*)d_ws;
    int* plist = (int*)((char*)d_ws + NM * sizeof(int));

    (void)hipMemsetAsync(count, 0, NM * sizeof(int), stream);
    k_bucket<<<NPTS / 256, 256, 0, stream>>>(pts, count, plist);
    k_mlp<<<NBLK, 256, 0, stream>>>(pts, vds, w0, b0, w1, b1, fw, fb, sw, sb,
                                    vw, vb, rw, rb, count, plist, out);
}

// Round 7
// 169.425 us; speedup vs baseline: 1.2383x; 1.0452x over previous
//
#include <hip/hip_runtime.h>

#define NM    4096
#define NPTS  131072
#define CAP   128

typedef _Float16 h8 __attribute__((ext_vector_type(8)));
typedef _Float16 h2 __attribute__((ext_vector_type(2)));
typedef float    f4 __attribute__((ext_vector_type(4)));
typedef int      i4 __attribute__((ext_vector_type(4)));

#define MF(a, b, c) __builtin_amdgcn_mfma_f32_16x16x32_f16((a), (b), (c), 0, 0, 0)

#if __has_builtin(__builtin_amdgcn_global_load_lds)
#define USE_DMA 1
#else
#define USE_DMA 0
#endif

static __device__ inline h2 pk(float a, float b) {
    return __builtin_bit_cast(h2, __builtin_amdgcn_cvt_pkrtz(a, b));
}

static __device__ inline h8 pack8(float u0, float u1, float u2, float u3,
                                  float u4, float u5, float u6, float u7) {
    i4 t;
    t[0] = __builtin_bit_cast(int, pk(u0, u1));
    t[1] = __builtin_bit_cast(int, pk(u2, u3));
    t[2] = __builtin_bit_cast(int, pk(u4, u5));
    t[3] = __builtin_bit_cast(int, pk(u6, u7));
    return __builtin_bit_cast(h8, t);
}

// 8 guarded f16 from an fp32 row in LDS (reads unconditional + select).
static __device__ inline h8 lds_row8(const float* __restrict__ X, int base,
                                     int d0, int lim) {
    float u[8];
    #pragma unroll
    for (int jj = 0; jj < 8; jj++) {
        int d = d0 + jj;
        float raw = X[base + d];          // always in-bounds of the 3040-f region
        u[jj] = (d < lim) ? raw : 0.f;
    }
    return pack8(u[0], u[1], u[2], u[3], u[4], u[5], u[6], u[7]);
}

// aligned 8-float (32B) run in LDS -> h8 (two ds_read_b128)
static __device__ inline h8 lds_row8a(const float* __restrict__ X, int off) {
    f4 v0 = *(const f4*)(X + off);
    f4 v1 = *(const f4*)(X + off + 4);
    return pack8(v0[0], v0[1], v0[2], v0[3], v1[0], v1[1], v1[2], v1[3]);
}

// 8 guarded f16 from a global fp32 row (fallback path, no DMA builtin).
static __device__ inline h8 load_row8(const float* __restrict__ rb, int d0, int lim) {
    float u[8];
    #pragma unroll
    for (int jj = 0; jj < 8; jj++) {
        int d = d0 + jj;
        u[jj] = (d < lim) ? rb[d] : 0.f;
    }
    return pack8(u[0], u[1], u[2], u[3], u[4], u[5], u[6], u[7]);
}

// NeRF frequency-encoding dim d of (x,y,z); 0 for d >= lim.
static __device__ inline float encdim(int d, int lim, float x, float y, float z) {
    int tt = d - 3;
    int k  = tt / 6;
    int r  = tt - 6 * k;
    float p = x;
    p = (r == 1 || r == 4) ? y : p;
    p = (r == 2 || r == 5) ? z : p;
    float f   = __int_as_float((k + 127) << 23);   // 2^k
    float arg = p * f + ((r >= 3) ? 1.57079632679f : 0.f);  // cos = sin(+pi/2)
    float sv  = __sinf(arg);
    float raw = (d == 0) ? x : ((d == 1) ? y : z);
    float val = (d < 3) ? raw : sv;
    return (d < lim) ? val : 0.f;
}

// D-frag pair -> B-frag (verified in R8; see R8 notes for derivation).
static __device__ inline h8 makeB(f4 d0, f4 d1, int quad, int col) {
    int laneA = ((quad & 1) * 2) * 16 + col;
    int laneB = laneA + 16;
    float a0 = __shfl(d0[0], laneA), b0 = __shfl(d1[0], laneA);
    float a1 = __shfl(d0[1], laneA), b1 = __shfl(d1[1], laneA);
    float a2 = __shfl(d0[2], laneA), b2 = __shfl(d1[2], laneA);
    float a3 = __shfl(d0[3], laneA), b3 = __shfl(d1[3], laneA);
    float a4 = __shfl(d0[0], laneB), b4 = __shfl(d1[0], laneB);
    float a5 = __shfl(d0[1], laneB), b5 = __shfl(d1[1], laneB);
    float a6 = __shfl(d0[2], laneB), b6 = __shfl(d1[2], laneB);
    float a7 = __shfl(d0[3], laneB), b7 = __shfl(d1[3], laneB);
    bool hi = quad >= 2;
    return pack8(hi ? b0 : a0, hi ? b1 : a1, hi ? b2 : a2, hi ? b3 : a3,
                 hi ? b4 : a4, hi ? b5 : a5, hi ? b6 : a6, hi ? b7 : a7);
}

static __device__ inline f4 relu4(f4 a) {
    f4 r;
    r[0] = fmaxf(a[0], 0.f); r[1] = fmaxf(a[1], 0.f);
    r[2] = fmaxf(a[2], 0.f); r[3] = fmaxf(a[3], 0.f);
    return r;
}

#if USE_DMA
static __device__ inline void dma16(const float* g, const float* l) {
    __builtin_amdgcn_global_load_lds(
        (const __attribute__((address_space(1))) void*)g,
        (__attribute__((address_space(3))) void*)l, 16, 0, 0);
}
#endif

__global__ __launch_bounds__(256) void k_bucket(const float* __restrict__ pts,
                                                int* __restrict__ count,
                                                int* __restrict__ plist) {
    int n = blockIdx.x * 256 + threadIdx.x;
    if (n >= NPTS) return;
    float x = pts[3 * n + 0], y = pts[3 * n + 1], z = pts[3 * n + 2];
    int ix = (int)fminf(fmaxf(x * 16.f, 0.f), 15.f);
    int iy = (int)fminf(fmaxf(y * 16.f, 0.f), 15.f);
    int iz = (int)fminf(fmaxf(z * 16.f, 0.f), 15.f);
    int v = (ix << 8) | (iy << 4) | iz;
    int pos = atomicAdd(&count[v], 1);
    if (pos < CAP) plist[v * CAP + pos] = n;
}

// R15 = R14 with the makeB retype-typo fixed (d1[0] -> d1[3]; R14's absmax
// 0.11 was exactly this: element 7 of every hi-quad B-fragment read acc row 0
// instead of row 3). Zero-barrier structure unchanged and still unmeasured.
//
// ZERO-BARRIER design — one wave per voxel, fully independent.
// R0/R9/R12 all pinned at 43-48 us & 1.45 TB/s regardless of staging scheme;
// the invariant was the intra-block barrier convoy. Here each wave owns one
// voxel + a private 12.2 KB LDS quarter; 12 independent wave-pipelines per CU
// desynchronize so memory drains and compute overlap ACROSS waves.
// Per wave: dma A (w0@0,w1@2016) ; gathers/biases/enc overlap ;
// vmcnt(0) [same-wave DMA->LDS visibility needs no barrier] ; unpack A ;
// lgkmcnt(0) [WAR: A-reads done before B overwrites] ; dma B
// (vw@0,fw@1888,sw@2912,rw@2944) ; layer0/layer1 (A-only) under B-flight ;
// vmcnt(0) ; unpack B ; sigma/feat/view/rgb ; remaining chunks.
// sched_barrier(0) after each inline s_waitcnt pins ordering (rule #18).
__global__ __launch_bounds__(256) void k_mlp(
    const float* __restrict__ pts, const float* __restrict__ vds,
    const float* __restrict__ w0g, const float* __restrict__ b0g,
    const float* __restrict__ w1g, const float* __restrict__ b1g,
    const float* __restrict__ fwg, const float* __restrict__ fbg,
    const float* __restrict__ swg, const float* __restrict__ sbg,
    const float* __restrict__ vwg, const float* __restrict__ vbg,
    const float* __restrict__ rwg, const float* __restrict__ rbg,
    const int* __restrict__ count, const int* __restrict__ plist,
    float* __restrict__ out) {
    __shared__ __align__(16) float X[4][3040];   // 48640 B, one quarter per wave

    const int t    = threadIdx.x;
    const int wid  = t >> 6;
    const int lane = t & 63;
    const int col  = lane & 15;
    const int quad = lane >> 4;
    const int k8   = quad * 8;
    const int v    = blockIdx.x * 4 + wid;
    const int c    = min(count[v], CAP);
    if (c == 0) return;                  // wave-uniform; no barriers anywhere
    float* Xw = X[wid];

#if USE_DMA
    // ---- stage A DMA: w0 (2016 f) @0, w1 (1024 f) @2016 ----
    {
        const float* g = w0g + (size_t)v * 2016;
        #pragma unroll
        for (int k = 0; k < 7; k++) dma16(g + k * 256 + lane * 4, Xw + k * 256);
        if (lane < 56) dma16(g + 1792 + lane * 4, Xw + 1792);
        const float* g1 = w1g + (size_t)v * 1024;
        #pragma unroll
        for (int k = 0; k < 4; k++) dma16(g1 + k * 256 + lane * 4, Xw + 2016 + k * 256);
    }
#endif

    // ---- chunk-0 point gathers + biases (overlap stage-A flight) ----
    int ncur = plist[v * CAP + min(col, c - 1)];
    float px = pts[3 * ncur], py = pts[3 * ncur + 1], pz = pts[3 * ncur + 2];
    int ray = ncur >> 7;
    float dx = vds[3 * ray], dy = vds[3 * ray + 1], dz = vds[3 * ray + 2];

    f4 cB0[2], cB1[2], cFB[2], cVB[2];
    #pragma unroll
    for (int Ti = 0; Ti < 2; Ti++) {
        int ro = v * 32 + Ti * 16 + quad * 4;          // 16B-aligned f4 rows
        cB0[Ti] = *(const f4*)(b0g + ro);
        cB1[Ti] = *(const f4*)(b1g + ro);
        cFB[Ti] = *(const f4*)(fbg + ro);
        cVB[Ti] = *(const f4*)(vbg + ro);
    }
    const float rb0 = rbg[v * 3 + 0], rb1 = rbg[v * 3 + 1], rb2 = rbg[v * 3 + 2];
    const float sb  = sbg[v];

    // ---- encodings for chunk 0 (compute while DMA flies) ----
    h8 bE0, bE1, bD;
    auto encode = [&](float qx, float qy, float qz, float ex, float ey, float ez) {
        bE0 = pack8(encdim(k8 + 0, 63, qx, qy, qz), encdim(k8 + 1, 63, qx, qy, qz),
                    encdim(k8 + 2, 63, qx, qy, qz), encdim(k8 + 3, 63, qx, qy, qz),
                    encdim(k8 + 4, 63, qx, qy, qz), encdim(k8 + 5, 63, qx, qy, qz),
                    encdim(k8 + 6, 63, qx, qy, qz), encdim(k8 + 7, 63, qx, qy, qz));
        bE1 = pack8(encdim(32 + k8 + 0, 63, qx, qy, qz), encdim(32 + k8 + 1, 63, qx, qy, qz),
                    encdim(32 + k8 + 2, 63, qx, qy, qz), encdim(32 + k8 + 3, 63, qx, qy, qz),
                    encdim(32 + k8 + 4, 63, qx, qy, qz), encdim(32 + k8 + 5, 63, qx, qy, qz),
                    encdim(32 + k8 + 6, 63, qx, qy, qz), encdim(32 + k8 + 7, 63, qx, qy, qz));
        bD  = pack8(encdim(k8 + 0, 27, ex, ey, ez), encdim(k8 + 1, 27, ex, ey, ez),
                    encdim(k8 + 2, 27, ex, ey, ez), encdim(k8 + 3, 27, ex, ey, ez),
                    encdim(k8 + 4, 27, ex, ey, ez), encdim(k8 + 5, 27, ex, ey, ez),
                    encdim(k8 + 6, 27, ex, ey, ez), encdim(k8 + 7, 27, ex, ey, ez));
    };
    encode(px, py, pz, dx, dy, dz);

    h8 aW0[2][2], aW1[2], aVW[2][2], aFW[2], aSG, aRGB;

#if USE_DMA
    asm volatile("s_waitcnt vmcnt(0)" ::: "memory");   // stage A landed
    __builtin_amdgcn_sched_barrier(0);
    #pragma unroll
    for (int Ti = 0; Ti < 2; Ti++) {
        int r0 = (Ti * 16 + col) * 63;
        aW0[Ti][0] = lds_row8(Xw, r0, k8, 63);
        aW0[Ti][1] = lds_row8(Xw, r0, 32 + k8, 63);
        aW1[Ti] = lds_row8a(Xw, 2016 + (Ti * 16 + col) * 32 + k8);
    }
    asm volatile("s_waitcnt lgkmcnt(0)" ::: "memory"); // A-reads done before B overwrite
    __builtin_amdgcn_sched_barrier(0);

    // ---- stage B DMA: vw @0, fw @1888, sw @2912, rw @2944 ----
    {
        const float* g = vwg + (size_t)v * 1888;
        #pragma unroll
        for (int k = 0; k < 7; k++) dma16(g + k * 256 + lane * 4, Xw + k * 256);
        if (lane < 24) dma16(g + 1792 + lane * 4, Xw + 1792);
        const float* g1 = fwg + (size_t)v * 1024;
        #pragma unroll
        for (int k = 0; k < 4; k++) dma16(g1 + k * 256 + lane * 4, Xw + 1888 + k * 256);
        if (lane < 8)  dma16(swg + (size_t)v * 32 + lane * 4, Xw + 2912);
        if (lane < 24) dma16(rwg + (size_t)v * 96 + lane * 4, Xw + 2944);
    }
#else
    {
        #pragma unroll
        for (int Ti = 0; Ti < 2; Ti++) {
            const float* rb = w0g + (size_t)v * 2016 + (Ti * 16 + col) * 63;
            aW0[Ti][0] = load_row8(rb, k8, 63);
            aW0[Ti][1] = load_row8(rb, 32 + k8, 63);
            aW1[Ti] = load_row8(w1g + (size_t)v * 1024 + (Ti * 16 + col) * 32, k8, 32);
        }
    }
#endif

    const f4 z4 = {0.f, 0.f, 0.f, 0.f};

    // ---- chunk 0, phase A: layers 0/1 need only stage-A fragments ----
    f4 d0 = MF(aW0[0][0], bE0, cB0[0]); d0 = MF(aW0[0][1], bE1, d0);
    f4 d1 = MF(aW0[1][0], bE0, cB0[1]); d1 = MF(aW0[1][1], bE1, d1);
    d0 = relu4(d0); d1 = relu4(d1);
    h8 bH = makeB(d0, d1, quad, col);
    f4 e0 = MF(aW1[0], bH, cB1[0]);
    f4 e1 = MF(aW1[1], bH, cB1[1]);
    e0 = relu4(e0); e1 = relu4(e1);
    h8 bG = makeB(e0, e1, quad, col);

#if USE_DMA
    asm volatile("s_waitcnt vmcnt(0)" ::: "memory");   // stage B landed
    __builtin_amdgcn_sched_barrier(0);
    #pragma unroll
    for (int Ti = 0; Ti < 2; Ti++) {
        int r1 = (Ti * 16 + col) * 59;
        aVW[Ti][0] = lds_row8(Xw, r1, k8, 59);
        aVW[Ti][1] = lds_row8(Xw, r1, 32 + k8, 59);
        aFW[Ti] = lds_row8a(Xw, 1888 + (Ti * 16 + col) * 32 + k8);
    }
    aSG  = (col == 0) ? lds_row8a(Xw, 2912 + k8) : h8{};
    aRGB = (col < 3) ? lds_row8a(Xw, 2944 + col * 32 + k8) : h8{};
#else
    {
        #pragma unroll
        for (int Ti = 0; Ti < 2; Ti++) {
            const float* rb = vwg + (size_t)v * 1888 + (Ti * 16 + col) * 59;
            aVW[Ti][0] = load_row8(rb, k8, 59);
            aVW[Ti][1] = load_row8(rb, 32 + k8, 59);
            aFW[Ti] = load_row8(fwg + (size_t)v * 1024 + (Ti * 16 + col) * 32, k8, 32);
        }
        aSG  = (col == 0) ? load_row8(swg + (size_t)v * 32, k8, 32) : h8{};
        aRGB = (col < 3) ? load_row8(rwg + (size_t)v * 96 + col * 32, k8, 32) : h8{};
    }
#endif

    // ---- chunk 0, phase B ----
    {
        f4 s  = MF(aSG, bG, z4);
        f4 f0 = MF(aFW[0], bG, cFB[0]);
        f4 f1 = MF(aFW[1], bG, cFB[1]);
        h8 bF = makeB(f0, f1, quad, col);
        f4 v0 = MF(aVW[0][0], bF, cVB[0]); v0 = MF(aVW[0][1], bD, v0);
        f4 v1 = MF(aVW[1][0], bF, cVB[1]); v1 = MF(aVW[1][1], bD, v1);
        v0 = relu4(v0); v1 = relu4(v1);
        h8 bV = makeB(v0, v1, quad, col);
        f4 o  = MF(aRGB, bV, z4);
        if (quad == 0 && col < c) {
            out[3 * ncur + 0] = o[0] + rb0;
            out[3 * ncur + 1] = o[1] + rb1;
            out[3 * ncur + 2] = o[2] + rb2;
            out[3 * NPTS + ncur] = s[0] + sb;
        }
    }

    // ---- remaining chunks (c > 16) ----
    for (int base = 16; base < c; base += 16) {
        int n = plist[v * CAP + min(base + col, c - 1)];
        const bool active = (base + col) < c;
        float qx = pts[3 * n], qy = pts[3 * n + 1], qz = pts[3 * n + 2];
        int r2 = n >> 7;
        float ex = vds[3 * r2], ey = vds[3 * r2 + 1], ez = vds[3 * r2 + 2];
        encode(qx, qy, qz, ex, ey, ez);

        d0 = MF(aW0[0][0], bE0, cB0[0]); d0 = MF(aW0[0][1], bE1, d0);
        d1 = MF(aW0[1][0], bE0, cB0[1]); d1 = MF(aW0[1][1], bE1, d1);
        d0 = relu4(d0); d1 = relu4(d1);
        bH = makeB(d0, d1, quad, col);

        e0 = MF(aW1[0], bH, cB1[0]);
        e1 = MF(aW1[1], bH, cB1[1]);
        e0 = relu4(e0); e1 = relu4(e1);
        bG = makeB(e0, e1, quad, col);

        f4 s  = MF(aSG, bG, z4);
        f4 f0 = MF(aFW[0], bG, cFB[0]);
        f4 f1 = MF(aFW[1], bG, cFB[1]);
        h8 bF = makeB(f0, f1, quad, col);

        f4 v0 = MF(aVW[0][0], bF, cVB[0]); v0 = MF(aVW[0][1], bD, v0);
        f4 v1 = MF(aVW[1][0], bF, cVB[1]); v1 = MF(aVW[1][1], bD, v1);
        v0 = relu4(v0); v1 = relu4(v1);
        h8 bV = makeB(v0, v1, quad, col);
        f4 o  = MF(aRGB, bV, z4);

        if (quad == 0 && active) {
            out[3 * n + 0] = o[0] + rb0;
            out[3 * n + 1] = o[1] + rb1;
            out[3 * n + 2] = o[2] + rb2;
            out[3 * NPTS + n] = s[0] + sb;
        }
    }
}

extern "C" void kernel_launch(void* const* d_in, const int* in_sizes, int n_in,
                              void* d_out, int out_size, void* d_ws, size_t ws_size,
                              hipStream_t stream) {
    const float* pts = (const float*)d_in[0];
    const float* vds = (const float*)d_in[1];
    const float* w0  = (const float*)d_in[2];
    const float* b0  = (const float*)d_in[3];
    const float* w1  = (const float*)d_in[4];
    const float* b1  = (const float*)d_in[5];
    const float* fw  = (const float*)d_in[6];
    const float* fb  = (const float*)d_in[7];
    const float* sw  = (const float*)d_in[8];
    const float* sb  = (const float*)d_in[9];
    const float* vw  = (const float*)d_in[10];
    const float* vb  = (const float*)d_in[11];
    const float* rw  = (const float*)d_in[12];
    const float* rb  = (const float*)d_in[13];
    float* out = (float*)d_out;

    int* count = (int*)d_ws;
    int* plist = (int*)((char*)d_ws + NM * sizeof(int));

    (void)hipMemsetAsync(count, 0, NM * sizeof(int), stream);
    k_bucket<<<NPTS / 256, 256, 0, stream>>>(pts, count, plist);
    k_mlp<<<NM / 4, 256, 0, stream>>>(pts, vds, w0, b0, w1, b1, fw, fb, sw, sb,
                                      vw, vb, rw, rb, count, plist, out);
}

// Round 8
// 165.340 us; speedup vs baseline: 1.2689x; 1.0247x over previous
//
#include <hip/hip_runtime.h>

#define NM    4096
#define NPTS  131072
#define CAP   128

typedef _Float16 h8 __attribute__((ext_vector_type(8)));
typedef _Float16 h2 __attribute__((ext_vector_type(2)));
typedef float    f4 __attribute__((ext_vector_type(4)));
typedef int      i4 __attribute__((ext_vector_type(4)));

#define MF(a, b, c) __builtin_amdgcn_mfma_f32_16x16x32_f16((a), (b), (c), 0, 0, 0)

#if __has_builtin(__builtin_amdgcn_global_load_lds)
#define USE_DMA 1
#else
#define USE_DMA 0
#endif

static __device__ inline h2 pk(float a, float b) {
    return __builtin_bit_cast(h2, __builtin_amdgcn_cvt_pkrtz(a, b));
}

static __device__ inline h8 pack8(float u0, float u1, float u2, float u3,
                                  float u4, float u5, float u6, float u7) {
    i4 t;
    t[0] = __builtin_bit_cast(int, pk(u0, u1));
    t[1] = __builtin_bit_cast(int, pk(u2, u3));
    t[2] = __builtin_bit_cast(int, pk(u4, u5));
    t[3] = __builtin_bit_cast(int, pk(u6, u7));
    return __builtin_bit_cast(h8, t);
}

// 8 guarded f16 from an fp32 row in LDS (reads unconditional + select).
static __device__ inline h8 lds_row8(const float* __restrict__ X, int base,
                                     int d0, int lim) {
    float u[8];
    #pragma unroll
    for (int jj = 0; jj < 8; jj++) {
        int d = d0 + jj;
        float raw = X[base + d];          // always in-bounds of the 3040-f region
        u[jj] = (d < lim) ? raw : 0.f;
    }
    return pack8(u[0], u[1], u[2], u[3], u[4], u[5], u[6], u[7]);
}

// aligned 8-float (32B) run in LDS -> h8 (two ds_read_b128)
static __device__ inline h8 lds_row8a(const float* __restrict__ X, int off) {
    f4 v0 = *(const f4*)(X + off);
    f4 v1 = *(const f4*)(X + off + 4);
    return pack8(v0[0], v0[1], v0[2], v0[3], v1[0], v1[1], v1[2], v1[3]);
}

// 8 guarded f16 from a global fp32 row (fallback path, no DMA builtin).
static __device__ inline h8 load_row8(const float* __restrict__ rb, int d0, int lim) {
    float u[8];
    #pragma unroll
    for (int jj = 0; jj < 8; jj++) {
        int d = d0 + jj;
        u[jj] = (d < lim) ? rb[d] : 0.f;
    }
    return pack8(u[0], u[1], u[2], u[3], u[4], u[5], u[6], u[7]);
}

// NeRF frequency-encoding dim d of (x,y,z); 0 for d >= lim.
static __device__ inline float encdim(int d, int lim, float x, float y, float z) {
    int tt = d - 3;
    int k  = tt / 6;
    int r  = tt - 6 * k;
    float p = x;
    p = (r == 1 || r == 4) ? y : p;
    p = (r == 2 || r == 5) ? z : p;
    float f   = __int_as_float((k + 127) << 23);   // 2^k
    float arg = p * f + ((r >= 3) ? 1.57079632679f : 0.f);  // cos = sin(+pi/2)
    float sv  = __sinf(arg);
    float raw = (d == 0) ? x : ((d == 1) ? y : z);
    float val = (d < 3) ? raw : sv;
    return (d < lim) ? val : 0.f;
}

// D-frag pair -> B-frag (verified in R8; see R8 notes for derivation).
static __device__ inline h8 makeB(f4 d0, f4 d1, int quad, int col) {
    int laneA = ((quad & 1) * 2) * 16 + col;
    int laneB = laneA + 16;
    float a0 = __shfl(d0[0], laneA), b0 = __shfl(d1[0], laneA);
    float a1 = __shfl(d0[1], laneA), b1 = __shfl(d1[1], laneA);
    float a2 = __shfl(d0[2], laneA), b2 = __shfl(d1[2], laneA);
    float a3 = __shfl(d0[3], laneA), b3 = __shfl(d1[3], laneA);
    float a4 = __shfl(d0[0], laneB), b4 = __shfl(d1[0], laneB);
    float a5 = __shfl(d0[1], laneB), b5 = __shfl(d1[1], laneB);
    float a6 = __shfl(d0[2], laneB), b6 = __shfl(d1[2], laneB);
    float a7 = __shfl(d0[3], laneB), b7 = __shfl(d1[3], laneB);
    bool hi = quad >= 2;
    return pack8(hi ? b0 : a0, hi ? b1 : a1, hi ? b2 : a2, hi ? b3 : a3,
                 hi ? b4 : a4, hi ? b5 : a5, hi ? b6 : a6, hi ? b7 : a7);
}

static __device__ inline f4 relu4(f4 a) {
    f4 r;
    r[0] = fmaxf(a[0], 0.f); r[1] = fmaxf(a[1], 0.f);
    r[2] = fmaxf(a[2], 0.f); r[3] = fmaxf(a[3], 0.f);
    return r;
}

#if USE_DMA
static __device__ inline void dma16(const float* g, const float* l) {
    __builtin_amdgcn_global_load_lds(
        (const __attribute__((address_space(1))) void*)g,
        (__attribute__((address_space(3))) void*)l, 16, 0, 0);
}
#endif

__global__ __launch_bounds__(256) void k_bucket(const float* __restrict__ pts,
                                                int* __restrict__ count,
                                                int* __restrict__ plist) {
    int n = blockIdx.x * 256 + threadIdx.x;
    if (n >= NPTS) return;
    float x = pts[3 * n + 0], y = pts[3 * n + 1], z = pts[3 * n + 2];
    int ix = (int)fminf(fmaxf(x * 16.f, 0.f), 15.f);
    int iy = (int)fminf(fmaxf(y * 16.f, 0.f), 15.f);
    int iz = (int)fminf(fmaxf(z * 16.f, 0.f), 15.f);
    int v = (ix << 8) | (iy << 4) | iz;
    int pos = atomicAdd(&count[v], 1);
    if (pos < CAP) plist[v * CAP + pos] = n;
}

// R16: TLP + gather-chain fix on the (verified-correct) R15 dataflow.
// R15 post-mortem: all 4 structures pin at ~41-48us; VALUBusy 16% at ~1.2
// waves/SIMD -> waves stalled 87% of life; per-chunk plist->pts->vds DEPENDENT
// gather chain (~2000cyc) + DMA waits dominate; LDS 48.6KB/block capped
// residency at 3 blocks/CU. Fixes:
//  1. 1-wave blocks (64 thr): LDS 12.2 KB/block -> 13 blocks/CU resident.
//  2. plist row loaded ONCE via 2 unguarded coalesced loads; per-chunk
//     indices via __shfl broadcast (clamp in the shfl source lane) -> the
//     plist load leaves the per-chunk critical path entirely.
//  3. Next-chunk pts/vds prefetch (R0 pattern): gathers for chunk j+1 issue
//     before chunk j's compute.
// Per-wave phases unchanged from R15: dma A (w0@0,w1@2016); gathers/biases/
// enc overlap; vmcnt(0); unpack A; lgkmcnt(0); dma B (vw@0,fw@1888,sw@2912,
// rw@2944); L0/L1 chunk0 under B-flight; vmcnt(0); unpack B; finish chunk0;
// chunk loop with prefetch. sched_barrier(0) after inline waits (rule #18).
__global__ __launch_bounds__(64) void k_mlp(
    const float* __restrict__ pts, const float* __restrict__ vds,
    const float* __restrict__ w0g, const float* __restrict__ b0g,
    const float* __restrict__ w1g, const float* __restrict__ b1g,
    const float* __restrict__ fwg, const float* __restrict__ fbg,
    const float* __restrict__ swg, const float* __restrict__ sbg,
    const float* __restrict__ vwg, const float* __restrict__ vbg,
    const float* __restrict__ rwg, const float* __restrict__ rbg,
    const int* __restrict__ count, const int* __restrict__ plist,
    float* __restrict__ out) {
    __shared__ __align__(16) float X[3040];   // 12160 B -> 13 blocks/CU

    const int lane = threadIdx.x & 63;
    const int col  = lane & 15;
    const int quad = lane >> 4;
    const int k8   = quad * 8;
    const int v    = blockIdx.x;
    const int c    = min(count[v], CAP);
    if (c == 0) return;

#if USE_DMA
    // ---- stage A DMA: w0 (2016 f) @0, w1 (1024 f) @2016 ----
    {
        const float* g = w0g + (size_t)v * 2016;
        #pragma unroll
        for (int k = 0; k < 7; k++) dma16(g + k * 256 + lane * 4, X + k * 256);
        if (lane < 56) dma16(g + 1792 + lane * 4, X + 1792);
        const float* g1 = w1g + (size_t)v * 1024;
        #pragma unroll
        for (int k = 0; k < 4; k++) dma16(g1 + k * 256 + lane * 4, X + 2016 + k * 256);
    }
#endif

    // ---- whole plist row, unguarded coalesced (CAP=128 always allocated);
    //      entries >= c are garbage but never selected (clamped shfl lane) ----
    const int prow0 = plist[v * CAP + lane];
    const int prow1 = plist[v * CAP + 64 + lane];
    auto chunk_idx = [&](int base) -> int {
        int e = min(base + col, c - 1);
        int a = __shfl(prow0, e);
        int b = __shfl(prow1, e - 64);
        return (e < 64) ? a : b;
    };

    // ---- biases (aligned f4 rows) ----
    f4 cB0[2], cB1[2], cFB[2], cVB[2];
    #pragma unroll
    for (int Ti = 0; Ti < 2; Ti++) {
        int ro = v * 32 + Ti * 16 + quad * 4;
        cB0[Ti] = *(const f4*)(b0g + ro);
        cB1[Ti] = *(const f4*)(b1g + ro);
        cFB[Ti] = *(const f4*)(fbg + ro);
        cVB[Ti] = *(const f4*)(vbg + ro);
    }
    const float rb0 = rbg[v * 3 + 0], rb1 = rbg[v * 3 + 1], rb2 = rbg[v * 3 + 2];
    const float sb  = sbg[v];

    // ---- chunk-0 point data + chunk-1 prefetch (overlap stage-A flight) ----
    int ncur = chunk_idx(0);
    float px = pts[3 * ncur], py = pts[3 * ncur + 1], pz = pts[3 * ncur + 2];
    int ray = ncur >> 7;
    float dx = vds[3 * ray], dy = vds[3 * ray + 1], dz = vds[3 * ray + 2];

    int nnxt = 0;
    float qx = 0.f, qy = 0.f, qz = 0.f, ex = 0.f, ey = 0.f, ez = 0.f;
    if (16 < c) {
        nnxt = chunk_idx(16);
        qx = pts[3 * nnxt]; qy = pts[3 * nnxt + 1]; qz = pts[3 * nnxt + 2];
        int r2 = nnxt >> 7;
        ex = vds[3 * r2]; ey = vds[3 * r2 + 1]; ez = vds[3 * r2 + 2];
    }

    // ---- encodings for chunk 0 (compute while DMA flies) ----
    h8 bE0, bE1, bD;
    auto encode = [&](float sx, float sy, float sz, float tx, float ty, float tz) {
        bE0 = pack8(encdim(k8 + 0, 63, sx, sy, sz), encdim(k8 + 1, 63, sx, sy, sz),
                    encdim(k8 + 2, 63, sx, sy, sz), encdim(k8 + 3, 63, sx, sy, sz),
                    encdim(k8 + 4, 63, sx, sy, sz), encdim(k8 + 5, 63, sx, sy, sz),
                    encdim(k8 + 6, 63, sx, sy, sz), encdim(k8 + 7, 63, sx, sy, sz));
        bE1 = pack8(encdim(32 + k8 + 0, 63, sx, sy, sz), encdim(32 + k8 + 1, 63, sx, sy, sz),
                    encdim(32 + k8 + 2, 63, sx, sy, sz), encdim(32 + k8 + 3, 63, sx, sy, sz),
                    encdim(32 + k8 + 4, 63, sx, sy, sz), encdim(32 + k8 + 5, 63, sx, sy, sz),
                    encdim(32 + k8 + 6, 63, sx, sy, sz), encdim(32 + k8 + 7, 63, sx, sy, sz));
        bD  = pack8(encdim(k8 + 0, 27, tx, ty, tz), encdim(k8 + 1, 27, tx, ty, tz),
                    encdim(k8 + 2, 27, tx, ty, tz), encdim(k8 + 3, 27, tx, ty, tz),
                    encdim(k8 + 4, 27, tx, ty, tz), encdim(k8 + 5, 27, tx, ty, tz),
                    encdim(k8 + 6, 27, tx, ty, tz), encdim(k8 + 7, 27, tx, ty, tz));
    };
    encode(px, py, pz, dx, dy, dz);

    h8 aW0[2][2], aW1[2], aVW[2][2], aFW[2], aSG, aRGB;

#if USE_DMA
    asm volatile("s_waitcnt vmcnt(0)" ::: "memory");   // stage A landed
    __builtin_amdgcn_sched_barrier(0);
    #pragma unroll
    for (int Ti = 0; Ti < 2; Ti++) {
        int r0 = (Ti * 16 + col) * 63;
        aW0[Ti][0] = lds_row8(X, r0, k8, 63);
        aW0[Ti][1] = lds_row8(X, r0, 32 + k8, 63);
        aW1[Ti] = lds_row8a(X, 2016 + (Ti * 16 + col) * 32 + k8);
    }
    asm volatile("s_waitcnt lgkmcnt(0)" ::: "memory"); // A-reads done before B overwrite
    __builtin_amdgcn_sched_barrier(0);

    // ---- stage B DMA: vw @0, fw @1888, sw @2912, rw @2944 ----
    {
        const float* g = vwg + (size_t)v * 1888;
        #pragma unroll
        for (int k = 0; k < 7; k++) dma16(g + k * 256 + lane * 4, X + k * 256);
        if (lane < 24) dma16(g + 1792 + lane * 4, X + 1792);
        const float* g1 = fwg + (size_t)v * 1024;
        #pragma unroll
        for (int k = 0; k < 4; k++) dma16(g1 + k * 256 + lane * 4, X + 1888 + k * 256);
        if (lane < 8)  dma16(swg + (size_t)v * 32 + lane * 4, X + 2912);
        if (lane < 24) dma16(rwg + (size_t)v * 96 + lane * 4, X + 2944);
    }
#else
    {
        #pragma unroll
        for (int Ti = 0; Ti < 2; Ti++) {
            const float* rb = w0g + (size_t)v * 2016 + (Ti * 16 + col) * 63;
            aW0[Ti][0] = load_row8(rb, k8, 63);
            aW0[Ti][1] = load_row8(rb, 32 + k8, 63);
            aW1[Ti] = load_row8(w1g + (size_t)v * 1024 + (Ti * 16 + col) * 32, k8, 32);
        }
    }
#endif

    const f4 z4 = {0.f, 0.f, 0.f, 0.f};

    // ---- chunk 0, phase A: layers 0/1 need only stage-A fragments ----
    f4 d0 = MF(aW0[0][0], bE0, cB0[0]); d0 = MF(aW0[0][1], bE1, d0);
    f4 d1 = MF(aW0[1][0], bE0, cB0[1]); d1 = MF(aW0[1][1], bE1, d1);
    d0 = relu4(d0); d1 = relu4(d1);
    h8 bH = makeB(d0, d1, quad, col);
    f4 e0 = MF(aW1[0], bH, cB1[0]);
    f4 e1 = MF(aW1[1], bH, cB1[1]);
    e0 = relu4(e0); e1 = relu4(e1);
    h8 bG = makeB(e0, e1, quad, col);

#if USE_DMA
    asm volatile("s_waitcnt vmcnt(0)" ::: "memory");   // stage B landed
    __builtin_amdgcn_sched_barrier(0);
    #pragma unroll
    for (int Ti = 0; Ti < 2; Ti++) {
        int r1 = (Ti * 16 + col) * 59;
        aVW[Ti][0] = lds_row8(X, r1, k8, 59);
        aVW[Ti][1] = lds_row8(X, r1, 32 + k8, 59);
        aFW[Ti] = lds_row8a(X, 1888 + (Ti * 16 + col) * 32 + k8);
    }
    aSG  = (col == 0) ? lds_row8a(X, 2912 + k8) : h8{};
    aRGB = (col < 3) ? lds_row8a(X, 2944 + col * 32 + k8) : h8{};
#else
    {
        #pragma unroll
        for (int Ti = 0; Ti < 2; Ti++) {
            const float* rb = vwg + (size_t)v * 1888 + (Ti * 16 + col) * 59;
            aVW[Ti][0] = load_row8(rb, k8, 59);
            aVW[Ti][1] = load_row8(rb, 32 + k8, 59);
            aFW[Ti] = load_row8(fwg + (size_t)v * 1024 + (Ti * 16 + col) * 32, k8, 32);
        }
        aSG  = (col == 0) ? load_row8(swg + (size_t)v * 32, k8, 32) : h8{};
        aRGB = (col < 3) ? load_row8(rwg + (size_t)v * 96 + col * 32, k8, 32) : h8{};
    }
#endif

    // ---- chunk 0, phase B ----
    {
        f4 s  = MF(aSG, bG, z4);
        f4 f0 = MF(aFW[0], bG, cFB[0]);
        f4 f1 = MF(aFW[1], bG, cFB[1]);
        h8 bF = makeB(f0, f1, quad, col);
        f4 v0 = MF(aVW[0][0], bF, cVB[0]); v0 = MF(aVW[0][1], bD, v0);
        f4 v1 = MF(aVW[1][0], bF, cVB[1]); v1 = MF(aVW[1][1], bD, v1);
        v0 = relu4(v0); v1 = relu4(v1);
        h8 bV = makeB(v0, v1, quad, col);
        f4 o  = MF(aRGB, bV, z4);
        if (quad == 0 && col < c) {
            out[3 * ncur + 0] = o[0] + rb0;
            out[3 * ncur + 1] = o[1] + rb1;
            out[3 * ncur + 2] = o[2] + rb2;
            out[3 * NPTS + ncur] = s[0] + sb;
        }
    }

    // ---- remaining chunks, next-chunk point data prefetched ----
    for (int base = 16; base < c; base += 16) {
        // snapshot prefetched data BEFORE issuing next prefetch (R10 lesson)
        const int n = nnxt;
        const float cx = qx, cy = qy, cz = qz;
        const float fx = ex, fy = ey, fz = ez;

        if (base + 16 < c) {
            nnxt = chunk_idx(base + 16);
            qx = pts[3 * nnxt]; qy = pts[3 * nnxt + 1]; qz = pts[3 * nnxt + 2];
            int r2 = nnxt >> 7;
            ex = vds[3 * r2]; ey = vds[3 * r2 + 1]; ez = vds[3 * r2 + 2];
        }

        encode(cx, cy, cz, fx, fy, fz);

        d0 = MF(aW0[0][0], bE0, cB0[0]); d0 = MF(aW0[0][1], bE1, d0);
        d1 = MF(aW0[1][0], bE0, cB0[1]); d1 = MF(aW0[1][1], bE1, d1);
        d0 = relu4(d0); d1 = relu4(d1);
        bH = makeB(d0, d1, quad, col);

        e0 = MF(aW1[0], bH, cB1[0]);
        e1 = MF(aW1[1], bH, cB1[1]);
        e0 = relu4(e0); e1 = relu4(e1);
        bG = makeB(e0, e1, quad, col);

        f4 s  = MF(aSG, bG, z4);
        f4 f0 = MF(aFW[0], bG, cFB[0]);
        f4 f1 = MF(aFW[1], bG, cFB[1]);
        h8 bF = makeB(f0, f1, quad, col);

        f4 v0 = MF(aVW[0][0], bF, cVB[0]); v0 = MF(aVW[0][1], bD, v0);
        f4 v1 = MF(aVW[1][0], bF, cVB[1]); v1 = MF(aVW[1][1], bD, v1);
        v0 = relu4(v0); v1 = relu4(v1);
        h8 bV = makeB(v0, v1, quad, col);
        f4 o  = MF(aRGB, bV, z4);

        if (quad == 0 && (base + col) < c) {
            out[3 * n + 0] = o[0] + rb0;
            out[3 * n + 1] = o[1] + rb1;
            out[3 * n + 2] = o[2] + rb2;
            out[3 * NPTS + n] = s[0] + sb;
        }
    }
}

extern "C" void kernel_launch(void* const* d_in, const int* in_sizes, int n_in,
                              void* d_out, int out_size, void* d_ws, size_t ws_size,
                              hipStream_t stream) {
    const float* pts = (const float*)d_in[0];
    const float* vds = (const float*)d_in[1];
    const float* w0  = (const float*)d_in[2];
    const float* b0  = (const float*)d_in[3];
    const float* w1  = (const float*)d_in[4];
    const float* b1  = (const float*)d_in[5];
    const float* fw  = (const float*)d_in[6];
    const float* fb  = (const float*)d_in[7];
    const float* sw  = (const float*)d_in[8];
    const float* sb  = (const float*)d_in[9];
    const float* vw  = (const float*)d_in[10];
    const float* vb  = (const float*)d_in[11];
    const float* rw  = (const float*)d_in[12];
    const float* rb  = (const float*)d_in[13];
    float* out = (float*)d_out;

    int* count = (int*)d_ws;
    int* plist = (int*)((char*)d_ws + NM * sizeof(int));

    (void)hipMemsetAsync(count, 0, NM * sizeof(int), stream);
    k_bucket<<<NPTS / 256, 256, 0, stream>>>(pts, count, plist);
    k_mlp<<<NM, 64, 0, stream>>>(pts, vds, w0, b0, w1, b1, fw, fb, sw, sb,
                                 vw, vb, rw, rb, count, plist, out);
}